// Round 2
// 932.300 us; speedup vs baseline: 1.0452x; 1.0452x over previous
//
#include <hip/hip_runtime.h>
#include <stdint.h>
#include <stddef.h>

// ---------------------------------------------------------------------------
// GQA forward: y = Attn(RoPE(x@Wq), RoPE(x@Wk), x@Wv) @ Wo
// B=2 S=2048 D=4096 H=32 KVH=8 Dh=128, causal, fp32 in/out, bf16 MFMA compute.
// ---------------------------------------------------------------------------

typedef __bf16 bf16x8 __attribute__((ext_vector_type(8)));
typedef float floatx4 __attribute__((ext_vector_type(4)));
typedef unsigned short ushort8v __attribute__((ext_vector_type(8)));
typedef unsigned short ushort4v __attribute__((ext_vector_type(4)));
typedef unsigned short ushort2v __attribute__((ext_vector_type(2)));

#define DEV static __device__ __forceinline__

DEV unsigned short f2bf(float f) {
  union { float f; unsigned u; } v; v.f = f;
  unsigned r = v.u + 0x7fffu + ((v.u >> 16) & 1u);
  return (unsigned short)(r >> 16);
}
DEV float bf2f(unsigned short b) {
  union { unsigned u; float f; } v; v.u = ((unsigned)b) << 16;
  return v.f;
}

// async global->LDS, 16B per lane; lds dest is wave-uniform base + lane*16
DEV void gload_lds16(const void* g, void* lds) {
  __builtin_amdgcn_global_load_lds(
      (__attribute__((address_space(1))) void*)(g),
      (__attribute__((address_space(3))) void*)(lds), 16, 0, 0);
}

// ---------------------------------------------------------------------------
// fp32 -> bf16 elementwise (x)
// ---------------------------------------------------------------------------
__global__ __launch_bounds__(256) void cvt_fp32_bf16(
    const float* __restrict__ in, unsigned short* __restrict__ out, int n4) {
  int i = blockIdx.x * 256 + threadIdx.x;
  if (i >= n4) return;
  float4 v = ((const float4*)in)[i];
  ushort4v w;
  w.x = f2bf(v.x); w.y = f2bf(v.y); w.z = f2bf(v.z); w.w = f2bf(v.w);
  *(ushort4v*)(out + (size_t)i * 4) = w;
}

// ---------------------------------------------------------------------------
// fp32 (K x N) -> bf16 (N x K) tiled transpose+convert
// ---------------------------------------------------------------------------
__global__ __launch_bounds__(256) void transpose_cvt(
    const float* __restrict__ in, unsigned short* __restrict__ out, int K, int N) {
  __shared__ float tile[32][33];
  int k0 = blockIdx.x * 32, n0 = blockIdx.y * 32;
  int tx = threadIdx.x & 31, ty = threadIdx.x >> 5;
  for (int i = 0; i < 32; i += 8)
    tile[ty + i][tx] = in[(size_t)(k0 + ty + i) * N + n0 + tx];
  __syncthreads();
  for (int i = 0; i < 32; i += 8)
    out[(size_t)(n0 + ty + i) * K + k0 + tx] = f2bf(tile[tx][ty + i]);
}

// ---------------------------------------------------------------------------
// GEMM: C[M,N] = A[M,K] * B[K,N], with B supplied transposed (Bt[N,K]).
// bf16 inputs, fp32 accumulate. 128x128 tile, BK=32, 256 thr (4 waves, 2x2).
// LDS layout: row-major [128 rows][4 chunks of 8 k-elems], with the chunk
// position XOR-swizzled by (row&3):
//   position p of row r holds global k-chunk  q = p ^ (r&3).
// Write (global_load_lds, lane c of issue t): row = t*16 + (c>>2),
//   global chunk = (c&3) ^ ((c>>2)&3)  -> 4 lanes/row = contiguous 64 B
//   global segment (coalesced), LDS dest = base + c*16 (HW constraint).
// Read (fragment row rm, k-chunk quad): position = quad ^ (rm&3); bank
//   starts cycle {0,20,8,28} -> 8 words/bank/instr = the b128 floor.
// STORE_F32: 1 -> fp32 C, 0 -> bf16 C.
// ---------------------------------------------------------------------------
template <int STORE_F32>
__global__ __launch_bounds__(256, 2) void gemm_bt(
    const unsigned short* __restrict__ A, const unsigned short* __restrict__ Bt,
    void* __restrict__ Cp, int M, int N, int K) {
  __shared__ __align__(16) unsigned short a_lds[4096];  // [128][32], swizzled
  __shared__ __align__(16) unsigned short b_lds[4096];
  const int tid = threadIdx.x;
  const int wave = tid >> 6, lane = tid & 63;
  const int quad = lane >> 4, l16 = lane & 15;
  const int m0 = blockIdx.x * 128, n0 = blockIdx.y * 128;
  const int wm = (wave >> 1) * 64, wn = (wave & 1) * 64;

  // staging address components (per-thread constants)
  const int srow = (lane >> 2);                       // 0..15 within issue
  const int skq = (lane & 3) ^ ((lane >> 2) & 3);     // swizzled k-chunk

  floatx4 acc[4][4] = {};

  for (int k0 = 0; k0 < K; k0 += 32) {
    __syncthreads();
    for (int s = 0; s < 2; ++s) {
      int t = wave * 2 + s;            // issue id 0..7 -> rows t*16..t*16+15
      int row = t * 16 + srow;
      gload_lds16(A + (size_t)(m0 + row) * K + k0 + skq * 8, a_lds + t * 512);
      gload_lds16(Bt + (size_t)(n0 + row) * K + k0 + skq * 8, b_lds + t * 512);
    }
    __syncthreads();
    bf16x8 af[4], bfr[4];
    const int pos = (quad ^ (l16 & 3)) * 8;
    for (int i = 0; i < 4; ++i)
      af[i] = *(const bf16x8*)(a_lds + (wm + i * 16 + l16) * 32 + pos);
    for (int j = 0; j < 4; ++j)
      bfr[j] = *(const bf16x8*)(b_lds + (wn + j * 16 + l16) * 32 + pos);
    for (int i = 0; i < 4; ++i)
      for (int j = 0; j < 4; ++j)
        acc[i][j] =
            __builtin_amdgcn_mfma_f32_16x16x32_bf16(af[i], bfr[j], acc[i][j], 0, 0, 0);
  }

  for (int i = 0; i < 4; ++i)
    for (int j = 0; j < 4; ++j)
      for (int r = 0; r < 4; ++r) {
        int row = m0 + wm + i * 16 + quad * 4 + r;
        int col = n0 + wn + j * 16 + l16;
        float v = acc[i][j][r];
        if (STORE_F32)
          ((float*)Cp)[(size_t)row * N + col] = v;
        else
          ((unsigned short*)Cp)[(size_t)row * N + col] = f2bf(v);
      }
}

// ---------------------------------------------------------------------------
// RoPE Q: qkv bf16 (4096 x 6144) cols [0,4096) -> Q (b,h,s,128) bf16
// ---------------------------------------------------------------------------
__global__ __launch_bounds__(256) void rope_q(
    const unsigned short* __restrict__ qkv, const float* __restrict__ fc,
    const float* __restrict__ fs, unsigned short* __restrict__ Qd) {
  int gid = blockIdx.x * 256 + threadIdx.x;  // B*S*H*64 = 8388608
  int i = gid & 63;
  int h = (gid >> 6) & 31;
  int s = (gid >> 11) & 2047;
  int b = gid >> 22;
  int row = b * 2048 + s;
  ushort2v p = *(const ushort2v*)(qkv + (size_t)row * 6144 + h * 128 + 2 * i);
  float a = bf2f(p.x), bb = bf2f(p.y);
  float c = fc[s * 64 + i], sn = fs[s * 64 + i];
  ushort2v w;
  w.x = f2bf(a * c - bb * sn);
  w.y = f2bf(a * sn + bb * c);
  *(ushort2v*)(Qd + ((((size_t)b * 32 + h) * 2048 + s) * 128 + 2 * i)) = w;
}

// ---------------------------------------------------------------------------
// RoPE K: qkv cols [4096,5120) -> K (b,kvh,s,128) bf16
// ---------------------------------------------------------------------------
__global__ __launch_bounds__(256) void rope_k(
    const unsigned short* __restrict__ qkv, const float* __restrict__ fc,
    const float* __restrict__ fs, unsigned short* __restrict__ Kd) {
  int gid = blockIdx.x * 256 + threadIdx.x;  // B*S*KVH*64 = 2097152
  int i = gid & 63;
  int kvh = (gid >> 6) & 7;
  int s = (gid >> 9) & 2047;
  int b = gid >> 20;
  int row = b * 2048 + s;
  ushort2v p = *(const ushort2v*)(qkv + (size_t)row * 6144 + 4096 + kvh * 128 + 2 * i);
  float a = bf2f(p.x), bb = bf2f(p.y);
  float c = fc[s * 64 + i], sn = fs[s * 64 + i];
  ushort2v w;
  w.x = f2bf(a * c - bb * sn);
  w.y = f2bf(a * sn + bb * c);
  *(ushort2v*)(Kd + ((((size_t)b * 8 + kvh) * 2048 + s) * 128 + 2 * i)) = w;
}

// ---------------------------------------------------------------------------
// V transpose: qkv cols [5120,6144) (s-major) -> Vt (b,kvh,128,2048) d-major
// ---------------------------------------------------------------------------
__global__ __launch_bounds__(256) void vtrans(
    const unsigned short* __restrict__ qkv, unsigned short* __restrict__ Vt) {
  __shared__ unsigned short tile[32][33];
  int bk = blockIdx.z;                 // b*8+kvh
  int b = bk >> 3, kvh = bk & 7;
  int s0 = blockIdx.x * 32, d0 = blockIdx.y * 32;
  int tx = threadIdx.x & 31, ty = threadIdx.x >> 5;
  for (int i = 0; i < 32; i += 8)
    tile[ty + i][tx] =
        qkv[(size_t)(b * 2048 + s0 + ty + i) * 6144 + 5120 + kvh * 128 + d0 + tx];
  __syncthreads();
  for (int i = 0; i < 32; i += 8)
    Vt[((size_t)bk * 128 + d0 + ty + i) * 2048 + s0 + tx] = tile[tx][ty + i];
}

// ---------------------------------------------------------------------------
// Flash attention, causal, GQA. One block = (b, h, 128 q-rows); 8 waves each
// own 16 q-rows. 64-key iterations. Online softmax state per lane covers
// rows quad*4..quad*4+3 (replicated across the 16 lanes of a quad).
// Verified MFMA contract: a=A[m=l16][k=quad*8+j], b=Bt[n=l16][k=quad*8+j],
// D[row=quad*4+r][col=l16].
//
// vs previous version:
//  - QBLK 64 -> 128 (8 waves): staging + barriers amortized over 2x q-rows.
//  - async-STAGE split (T14): next K/V tile loaded to regs right after the
//    "tile visible" barrier; regs -> LDS at top of next iteration. The L2
//    latency hides under QK+softmax+PV instead of sitting between barriers.
//  - dropped the barrier between P-write and PV: p_lds is per-wave, intra-wave
//    LDS write->read ordering is compiler-handled (lgkmcnt).
//  - defer-max (T13, THR=8): skip o_acc rescale when max doesn't grow; P is
//    bounded by e^8, fine in bf16 (relative precision unchanged by scale).
//  - waves that are fully causal-masked in the last diagonal iteration skip
//    compute (barriers still executed by all waves).
// ---------------------------------------------------------------------------
__global__ __launch_bounds__(512, 4) void attn_kernel(
    const unsigned short* __restrict__ Q,   // (b,h,s,128)
    const unsigned short* __restrict__ Kd,  // (b,kvh,s,128)
    const unsigned short* __restrict__ Vt,  // (b,kvh,128,s)
    unsigned short* __restrict__ O) {       // (b*s, 4096)
  __shared__ __align__(16) unsigned short k_lds[64][136];   // [key][d] +pad
  __shared__ __align__(16) unsigned short v_lds[128][72];   // [d][key] +pad
  __shared__ __align__(16) unsigned short p_lds[8][16][72]; // per-wave P

  const int tid = threadIdx.x;
  const int wave = tid >> 6, lane = tid & 63;
  const int quad = lane >> 4, l16 = lane & 15;
  const int q0 = blockIdx.x * 128;
  const int h = blockIdx.y;
  const int b = blockIdx.z;
  const int kvh = h >> 2;
  const float scale = 0.08838834764831845f;  // 1/sqrt(128)

  const unsigned short* qrow =
      Q + (((size_t)b * 32 + h) * 2048 + q0 + wave * 16 + l16) * 128;
  bf16x8 qf[4];
  for (int t = 0; t < 4; ++t)
    qf[t] = *(const bf16x8*)(qrow + t * 32 + quad * 8);

  float m_i[4], l_i[4];
  for (int r = 0; r < 4; ++r) { m_i[r] = -3.0e38f; l_i[r] = 0.f; }
  floatx4 o_acc[8] = {};

  const unsigned short* kbase = Kd + ((size_t)b * 8 + kvh) * 2048 * 128;
  const unsigned short* vbase = Vt + ((size_t)b * 8 + kvh) * 128 * 2048;

  // staging-register addressing (per-thread constants):
  // K tile (64 keys x 128 d = 16KB): 512 thr x 2 chunks of 16B.
  //   chunk s covers key = s*32 + (tid>>4), d-chunk = tid&15.
  // V tile (128 d x 64 keys = 16KB): chunk s covers d = s*64 + (tid>>3),
  //   s-chunk = tid&7.
  const int kk = tid >> 4, kd = tid & 15;
  const int vd = tid >> 3, vs = tid & 7;

  ushort8v krg[2], vrg[2];
  // prologue: load tile kb=0 into regs
  krg[0] = *(const ushort8v*)(kbase + (size_t)kk * 128 + kd * 8);
  krg[1] = *(const ushort8v*)(kbase + (size_t)(kk + 32) * 128 + kd * 8);
  vrg[0] = *(const ushort8v*)(vbase + (size_t)vd * 2048 + vs * 8);
  vrg[1] = *(const ushort8v*)(vbase + (size_t)(vd + 64) * 2048 + vs * 8);

  const int kb_last = q0 + 64;  // last 64-key tile needed by rows q0..q0+127
  for (int kb = 0; kb <= kb_last; kb += 64) {
    __syncthreads();  // previous tile's readers done
    *(ushort8v*)&k_lds[kk][kd * 8] = krg[0];
    *(ushort8v*)&k_lds[kk + 32][kd * 8] = krg[1];
    *(ushort8v*)&v_lds[vd][vs * 8] = vrg[0];
    *(ushort8v*)&v_lds[vd + 64][vs * 8] = vrg[1];
    __syncthreads();  // tile visible
    if (kb < kb_last) {  // issue next tile's loads; latency hides under compute
      int nkb = kb + 64;
      krg[0] = *(const ushort8v*)(kbase + (size_t)(nkb + kk) * 128 + kd * 8);
      krg[1] = *(const ushort8v*)(kbase + (size_t)(nkb + kk + 32) * 128 + kd * 8);
      vrg[0] = *(const ushort8v*)(vbase + (size_t)vd * 2048 + nkb + vs * 8);
      vrg[1] = *(const ushort8v*)(vbase + (size_t)(vd + 64) * 2048 + nkb + vs * 8);
    }
    // wave fully causal-masked for this tile? (only possible on last iter)
    if (kb > q0 + wave * 16 + 15) continue;

    // S = scale * Q K^T  (16 q-rows x 64 keys per wave)
    float sv[4][4];
    for (int kt = 0; kt < 4; ++kt) {
      floatx4 a = {0.f, 0.f, 0.f, 0.f};
      for (int t = 0; t < 4; ++t) {
        bf16x8 kf = *(const bf16x8*)&k_lds[kt * 16 + l16][t * 32 + quad * 8];
        a = __builtin_amdgcn_mfma_f32_16x16x32_bf16(qf[t], kf, a, 0, 0, 0);
      }
      for (int r = 0; r < 4; ++r) sv[kt][r] = a[r] * scale;
    }
    if (kb + 63 > q0 + wave * 16) {  // tile touches the diagonal: causal mask
      for (int kt = 0; kt < 4; ++kt) {
        int kcol = kb + kt * 16 + l16;
        for (int r = 0; r < 4; ++r) {
          int qg = q0 + wave * 16 + quad * 4 + r;
          if (kcol > qg) sv[kt][r] -= 1.0e9f;
        }
      }
    }
    // online softmax with defer-max (THR=8)
    float mx[4];
    for (int r = 0; r < 4; ++r) {
      float m = fmaxf(fmaxf(sv[0][r], sv[1][r]), fmaxf(sv[2][r], sv[3][r]));
      for (int off = 1; off < 16; off <<= 1)
        m = fmaxf(m, __shfl_xor(m, off));
      mx[r] = m;
    }
    bool grow = false;
    for (int r = 0; r < 4; ++r) grow |= (mx[r] > m_i[r] + 8.f);
    if (__any(grow)) {
      for (int r = 0; r < 4; ++r) {
        float mnew = fmaxf(m_i[r], mx[r]);
        float alpha = __expf(m_i[r] - mnew);
        m_i[r] = mnew;
        l_i[r] *= alpha;
        for (int nb = 0; nb < 8; ++nb) o_acc[nb][r] *= alpha;
      }
    }
    for (int r = 0; r < 4; ++r) {
      float sum = 0.f;
      for (int kt = 0; kt < 4; ++kt) {
        float p = __expf(sv[kt][r] - m_i[r]);
        sv[kt][r] = p;
        sum += p;
      }
      for (int off = 1; off < 16; off <<= 1)
        sum += __shfl_xor(sum, off);
      l_i[r] += sum;
    }
    // P: C-layout -> LDS -> A-layout (m120 pattern); per-wave slice, so no
    // block barrier needed between write and read.
    for (int kt = 0; kt < 4; ++kt)
      for (int r = 0; r < 4; ++r)
        p_lds[wave][quad * 4 + r][kt * 16 + l16] = f2bf(sv[kt][r]);
    // O += P V
    for (int tk = 0; tk < 2; ++tk) {
      bf16x8 pa = *(const bf16x8*)&p_lds[wave][l16][tk * 32 + quad * 8];
      for (int nb = 0; nb < 8; ++nb) {
        bf16x8 vb = *(const bf16x8*)&v_lds[nb * 16 + l16][tk * 32 + quad * 8];
        o_acc[nb] = __builtin_amdgcn_mfma_f32_16x16x32_bf16(pa, vb, o_acc[nb], 0, 0, 0);
      }
    }
  }

  for (int nb = 0; nb < 8; ++nb)
    for (int r = 0; r < 4; ++r) {
      int row = b * 2048 + q0 + wave * 16 + quad * 4 + r;
      int col = h * 128 + nb * 16 + l16;
      O[(size_t)row * 4096 + col] = f2bf(o_acc[nb][r] / l_i[r]);
    }
}

// ---------------------------------------------------------------------------
// Launcher.  Workspace layout (144 MB, with aliasing):
//   [0,   32M)  xb  (x in bf16)           -> later reused as Q (b,h,s,d)
//   [32M, 80M)  wT  (qkv weights, N x K)  -> later reused as w_oT
//   [80M, 128M) qkv (4096 x 6144 bf16)    -> later reused as O (attn out)
//   [128M,136M) Kd  (b,kvh,s,d)
//   [136M,144M) Vt  (b,kvh,d,s)
// ---------------------------------------------------------------------------
extern "C" void kernel_launch(void* const* d_in, const int* in_sizes, int n_in,
                              void* d_out, int out_size, void* d_ws, size_t ws_size,
                              hipStream_t stream) {
  const float* x   = (const float*)d_in[0];
  const float* w_q = (const float*)d_in[1];
  const float* w_k = (const float*)d_in[2];
  const float* w_v = (const float*)d_in[3];
  const float* w_o = (const float*)d_in[4];
  const float* fc  = (const float*)d_in[5];
  const float* fs  = (const float*)d_in[6];
  (void)in_sizes; (void)n_in; (void)out_size; (void)ws_size;

  char* ws = (char*)d_ws;
  unsigned short* xb  = (unsigned short*)(ws);
  unsigned short* wT  = (unsigned short*)(ws + 33554432ull);
  unsigned short* qkv = (unsigned short*)(ws + 83886080ull);
  unsigned short* Kd  = (unsigned short*)(ws + 134217728ull);
  unsigned short* Vt  = (unsigned short*)(ws + 142606336ull);
  unsigned short* Qd  = xb;   // alias: xb dead after gemm1
  unsigned short* woT = wT;   // alias: wT dead after gemm1
  unsigned short* Ob  = qkv;  // alias: qkv dead after rope/vtrans

  cvt_fp32_bf16<<<16384, 256, 0, stream>>>(x, xb, 4194304);
  transpose_cvt<<<dim3(128, 128), 256, 0, stream>>>(w_q, wT, 4096, 4096);
  transpose_cvt<<<dim3(128, 32), 256, 0, stream>>>(w_k, wT + (size_t)4096 * 4096, 4096, 1024);
  transpose_cvt<<<dim3(128, 32), 256, 0, stream>>>(w_v, wT + (size_t)5120 * 4096, 4096, 1024);
  gemm_bt<0><<<dim3(32, 48), 256, 0, stream>>>(xb, wT, qkv, 4096, 6144, 4096);
  transpose_cvt<<<dim3(128, 128), 256, 0, stream>>>(w_o, woT, 4096, 4096);
  rope_q<<<32768, 256, 0, stream>>>(qkv, fc, fs, Qd);
  rope_k<<<8192, 256, 0, stream>>>(qkv, fc, fs, Kd);
  vtrans<<<dim3(64, 4, 16), 256, 0, stream>>>(qkv, Vt);
  attn_kernel<<<dim3(16, 32, 2), 512, 0, stream>>>(Qd, Kd, Vt, Ob);
  gemm_bt<1><<<dim3(32, 32), 256, 0, stream>>>(Ob, woT, d_out, 4096, 4096, 4096);
}

// Round 3
// 817.093 us; speedup vs baseline: 1.1926x; 1.1410x over previous
//
#include <hip/hip_runtime.h>
#include <stdint.h>
#include <stddef.h>

// ---------------------------------------------------------------------------
// GQA forward: y = Attn(RoPE(x@Wq), RoPE(x@Wk), x@Wv) @ Wo
// B=2 S=2048 D=4096 H=32 KVH=8 Dh=128, causal, fp32 in/out, bf16 MFMA compute.
// ---------------------------------------------------------------------------

typedef __bf16 bf16x8 __attribute__((ext_vector_type(8)));
typedef float floatx4 __attribute__((ext_vector_type(4)));
typedef unsigned short ushort8v __attribute__((ext_vector_type(8)));
typedef unsigned short ushort4v __attribute__((ext_vector_type(4)));
typedef unsigned short ushort2v __attribute__((ext_vector_type(2)));

#define DEV static __device__ __forceinline__

DEV unsigned short f2bf(float f) {
  union { float f; unsigned u; } v; v.f = f;
  unsigned r = v.u + 0x7fffu + ((v.u >> 16) & 1u);
  return (unsigned short)(r >> 16);
}
DEV float bf2f(unsigned short b) {
  union { unsigned u; float f; } v; v.u = ((unsigned)b) << 16;
  return v.f;
}

// async global->LDS, 16B per lane; lds dest is wave-uniform base + lane*16
DEV void gload_lds16(const void* g, void* lds) {
  __builtin_amdgcn_global_load_lds(
      (__attribute__((address_space(1))) void*)(g),
      (__attribute__((address_space(3))) void*)(lds), 16, 0, 0);
}

// ---------------------------------------------------------------------------
// fp32 -> bf16 elementwise (x)
// ---------------------------------------------------------------------------
__global__ __launch_bounds__(256) void cvt_fp32_bf16(
    const float* __restrict__ in, unsigned short* __restrict__ out, int n4) {
  int i = blockIdx.x * 256 + threadIdx.x;
  if (i >= n4) return;
  float4 v = ((const float4*)in)[i];
  ushort4v w;
  w.x = f2bf(v.x); w.y = f2bf(v.y); w.z = f2bf(v.z); w.w = f2bf(v.w);
  *(ushort4v*)(out + (size_t)i * 4) = w;
}

// ---------------------------------------------------------------------------
// fp32 (K x N) -> bf16 (N x K) tiled transpose+convert
// ---------------------------------------------------------------------------
__global__ __launch_bounds__(256) void transpose_cvt(
    const float* __restrict__ in, unsigned short* __restrict__ out, int K, int N) {
  __shared__ float tile[32][33];
  int k0 = blockIdx.x * 32, n0 = blockIdx.y * 32;
  int tx = threadIdx.x & 31, ty = threadIdx.x >> 5;
  for (int i = 0; i < 32; i += 8)
    tile[ty + i][tx] = in[(size_t)(k0 + ty + i) * N + n0 + tx];
  __syncthreads();
  for (int i = 0; i < 32; i += 8)
    out[(size_t)(n0 + ty + i) * K + k0 + tx] = f2bf(tile[tx][ty + i]);
}

// ---------------------------------------------------------------------------
// GEMM: C[M,N] = A[M,K] * B[K,N], with B supplied transposed (Bt[N,K]).
// bf16 inputs, fp32 accumulate. 128x128 tile, BK=32, 256 thr (4 waves, 2x2).
// LDS layout: row-major [128 rows][4 chunks of 8 k-elems], with the chunk
// position XOR-swizzled by (row&3):
//   position p of row r holds global k-chunk  q = p ^ (r&3).
// Write (global_load_lds, lane c of issue t): row = t*16 + (c>>2),
//   global chunk = (c&3) ^ ((c>>2)&3)  -> 4 lanes/row = contiguous 64 B
//   global segment (coalesced), LDS dest = base + c*16 (HW constraint).
// Read (fragment row rm, k-chunk quad): position = quad ^ (rm&3); bank
//   starts cycle {0,20,8,28} -> 8 words/bank/instr = the b128 floor.
// STORE_F32: 1 -> fp32 C, 0 -> bf16 C.
// ---------------------------------------------------------------------------
template <int STORE_F32>
__global__ __launch_bounds__(256, 2) void gemm_bt(
    const unsigned short* __restrict__ A, const unsigned short* __restrict__ Bt,
    void* __restrict__ Cp, int M, int N, int K) {
  __shared__ __align__(16) unsigned short a_lds[4096];  // [128][32], swizzled
  __shared__ __align__(16) unsigned short b_lds[4096];
  const int tid = threadIdx.x;
  const int wave = tid >> 6, lane = tid & 63;
  const int quad = lane >> 4, l16 = lane & 15;
  const int m0 = blockIdx.x * 128, n0 = blockIdx.y * 128;
  const int wm = (wave >> 1) * 64, wn = (wave & 1) * 64;

  // staging address components (per-thread constants)
  const int srow = (lane >> 2);                       // 0..15 within issue
  const int skq = (lane & 3) ^ ((lane >> 2) & 3);     // swizzled k-chunk

  floatx4 acc[4][4] = {};

  for (int k0 = 0; k0 < K; k0 += 32) {
    __syncthreads();
    for (int s = 0; s < 2; ++s) {
      int t = wave * 2 + s;            // issue id 0..7 -> rows t*16..t*16+15
      int row = t * 16 + srow;
      gload_lds16(A + (size_t)(m0 + row) * K + k0 + skq * 8, a_lds + t * 512);
      gload_lds16(Bt + (size_t)(n0 + row) * K + k0 + skq * 8, b_lds + t * 512);
    }
    __syncthreads();
    bf16x8 af[4], bfr[4];
    const int pos = (quad ^ (l16 & 3)) * 8;
    for (int i = 0; i < 4; ++i)
      af[i] = *(const bf16x8*)(a_lds + (wm + i * 16 + l16) * 32 + pos);
    for (int j = 0; j < 4; ++j)
      bfr[j] = *(const bf16x8*)(b_lds + (wn + j * 16 + l16) * 32 + pos);
    for (int i = 0; i < 4; ++i)
      for (int j = 0; j < 4; ++j)
        acc[i][j] =
            __builtin_amdgcn_mfma_f32_16x16x32_bf16(af[i], bfr[j], acc[i][j], 0, 0, 0);
  }

  for (int i = 0; i < 4; ++i)
    for (int j = 0; j < 4; ++j)
      for (int r = 0; r < 4; ++r) {
        int row = m0 + wm + i * 16 + quad * 4 + r;
        int col = n0 + wn + j * 16 + l16;
        float v = acc[i][j][r];
        if (STORE_F32)
          ((float*)Cp)[(size_t)row * N + col] = v;
        else
          ((unsigned short*)Cp)[(size_t)row * N + col] = f2bf(v);
      }
}

// ---------------------------------------------------------------------------
// RoPE Q: qkv bf16 (4096 x 6144) cols [0,4096) -> Q (b,h,s,128) bf16
// ---------------------------------------------------------------------------
__global__ __launch_bounds__(256) void rope_q(
    const unsigned short* __restrict__ qkv, const float* __restrict__ fc,
    const float* __restrict__ fs, unsigned short* __restrict__ Qd) {
  int gid = blockIdx.x * 256 + threadIdx.x;  // B*S*H*64 = 8388608
  int i = gid & 63;
  int h = (gid >> 6) & 31;
  int s = (gid >> 11) & 2047;
  int b = gid >> 22;
  int row = b * 2048 + s;
  ushort2v p = *(const ushort2v*)(qkv + (size_t)row * 6144 + h * 128 + 2 * i);
  float a = bf2f(p.x), bb = bf2f(p.y);
  float c = fc[s * 64 + i], sn = fs[s * 64 + i];
  ushort2v w;
  w.x = f2bf(a * c - bb * sn);
  w.y = f2bf(a * sn + bb * c);
  *(ushort2v*)(Qd + ((((size_t)b * 32 + h) * 2048 + s) * 128 + 2 * i)) = w;
}

// ---------------------------------------------------------------------------
// RoPE K: qkv cols [4096,5120) -> K (b,kvh,s,128) bf16
// ---------------------------------------------------------------------------
__global__ __launch_bounds__(256) void rope_k(
    const unsigned short* __restrict__ qkv, const float* __restrict__ fc,
    const float* __restrict__ fs, unsigned short* __restrict__ Kd) {
  int gid = blockIdx.x * 256 + threadIdx.x;  // B*S*KVH*64 = 2097152
  int i = gid & 63;
  int kvh = (gid >> 6) & 7;
  int s = (gid >> 9) & 2047;
  int b = gid >> 20;
  int row = b * 2048 + s;
  ushort2v p = *(const ushort2v*)(qkv + (size_t)row * 6144 + 4096 + kvh * 128 + 2 * i);
  float a = bf2f(p.x), bb = bf2f(p.y);
  float c = fc[s * 64 + i], sn = fs[s * 64 + i];
  ushort2v w;
  w.x = f2bf(a * c - bb * sn);
  w.y = f2bf(a * sn + bb * c);
  *(ushort2v*)(Kd + ((((size_t)b * 8 + kvh) * 2048 + s) * 128 + 2 * i)) = w;
}

// ---------------------------------------------------------------------------
// V transpose: qkv cols [5120,6144) (s-major) -> Vt (b,kvh,128,2048) d-major
// ---------------------------------------------------------------------------
__global__ __launch_bounds__(256) void vtrans(
    const unsigned short* __restrict__ qkv, unsigned short* __restrict__ Vt) {
  __shared__ unsigned short tile[32][33];
  int bk = blockIdx.z;                 // b*8+kvh
  int b = bk >> 3, kvh = bk & 7;
  int s0 = blockIdx.x * 32, d0 = blockIdx.y * 32;
  int tx = threadIdx.x & 31, ty = threadIdx.x >> 5;
  for (int i = 0; i < 32; i += 8)
    tile[ty + i][tx] =
        qkv[(size_t)(b * 2048 + s0 + ty + i) * 6144 + 5120 + kvh * 128 + d0 + tx];
  __syncthreads();
  for (int i = 0; i < 32; i += 8)
    Vt[((size_t)bk * 128 + d0 + ty + i) * 2048 + s0 + tx] = tile[tx][ty + i];
}

// ---------------------------------------------------------------------------
// Flash attention, causal, GQA. One block = (b, h, TWO paired q-tiles of 128
// rows each); 8 waves each own 16 q-rows. 64-key iterations.
//
// Causal load balancing: q-tile i costs 2i+2 key-iterations (2..32). A block
// processes tile pr then tile 15-pr sequentially -> every block does exactly
// 34 iterations. Grid = 8x32x2 = 512 blocks = 2 blocks/CU resident in ONE
// generation -> no tail imbalance (was: 1024 blocks, 2..32 units each,
// measured OccupancyPercent 21% of the 50% structural cap).
// Both passes share (b,kvh) K/V -> L2 reuse inside the block.
//
// Online softmax state per lane covers rows quad*4..quad*4+3 (replicated
// across the 16 lanes of a quad). Verified MFMA contract:
// a=A[m=l16][k=quad*8+j], b=Bt[n=l16][k=quad*8+j], D[row=quad*4+r][col=l16].
//
// Carried techniques: async-STAGE split (T14) via reg-staged K/V prefetch;
// 2 barriers/iter (p_lds is per-wave, no barrier before PV); defer-max
// (T13, THR=8); wave-level skip of fully-masked diagonal tiles.
// LDS pads (136/72) keep 16B alignment for ds_read_b128; the resulting
// bank pattern is uniform 8 dwords/bank = the b128 floor (not a conflict).
// ---------------------------------------------------------------------------
__global__ __launch_bounds__(512, 4) void attn_kernel(
    const unsigned short* __restrict__ Q,   // (b,h,s,128)
    const unsigned short* __restrict__ Kd,  // (b,kvh,s,128)
    const unsigned short* __restrict__ Vt,  // (b,kvh,128,s)
    unsigned short* __restrict__ O) {       // (b*s, 4096)
  __shared__ __align__(16) unsigned short k_lds[64][136];   // [key][d] +pad
  __shared__ __align__(16) unsigned short v_lds[128][72];   // [d][key] +pad
  __shared__ __align__(16) unsigned short p_lds[8][16][72]; // per-wave P

  const int tid = threadIdx.x;
  const int wave = tid >> 6, lane = tid & 63;
  const int quad = lane >> 4, l16 = lane & 15;
  const int pr = blockIdx.x;           // 0..7 -> q-tiles {pr, 15-pr}
  const int h = blockIdx.y;
  const int b = blockIdx.z;
  const int kvh = h >> 2;
  const float scale = 0.08838834764831845f;  // 1/sqrt(128)

  const unsigned short* kbase = Kd + ((size_t)b * 8 + kvh) * 2048 * 128;
  const unsigned short* vbase = Vt + ((size_t)b * 8 + kvh) * 128 * 2048;

  // staging-register addressing (per-thread constants):
  // K tile (64 keys x 128 d = 16KB): 512 thr x 2 chunks of 16B.
  //   chunk s covers key = s*32 + (tid>>4), d-chunk = tid&15.
  // V tile (128 d x 64 keys = 16KB): chunk s covers d = s*64 + (tid>>3),
  //   s-chunk = tid&7.
  const int kk = tid >> 4, kd = tid & 15;
  const int vd = tid >> 3, vs = tid & 7;

  for (int pass = 0; pass < 2; ++pass) {
    const int qt = pass == 0 ? pr : 15 - pr;
    const int q0 = qt * 128;

    const unsigned short* qrow =
        Q + (((size_t)b * 32 + h) * 2048 + q0 + wave * 16 + l16) * 128;
    bf16x8 qf[4];
    for (int t = 0; t < 4; ++t)
      qf[t] = *(const bf16x8*)(qrow + t * 32 + quad * 8);

    float m_i[4], l_i[4];
    for (int r = 0; r < 4; ++r) { m_i[r] = -3.0e38f; l_i[r] = 0.f; }
    floatx4 o_acc[8] = {};

    ushort8v krg[2], vrg[2];
    // prologue: load tile kb=0 into regs
    krg[0] = *(const ushort8v*)(kbase + (size_t)kk * 128 + kd * 8);
    krg[1] = *(const ushort8v*)(kbase + (size_t)(kk + 32) * 128 + kd * 8);
    vrg[0] = *(const ushort8v*)(vbase + (size_t)vd * 2048 + vs * 8);
    vrg[1] = *(const ushort8v*)(vbase + (size_t)(vd + 64) * 2048 + vs * 8);

    const int kb_last = q0 + 64;  // last 64-key tile needed by rows q0..q0+127
    for (int kb = 0; kb <= kb_last; kb += 64) {
      __syncthreads();  // previous tile's readers done
      *(ushort8v*)&k_lds[kk][kd * 8] = krg[0];
      *(ushort8v*)&k_lds[kk + 32][kd * 8] = krg[1];
      *(ushort8v*)&v_lds[vd][vs * 8] = vrg[0];
      *(ushort8v*)&v_lds[vd + 64][vs * 8] = vrg[1];
      __syncthreads();  // tile visible
      if (kb < kb_last) {  // issue next tile's loads; latency hides under compute
        int nkb = kb + 64;
        krg[0] = *(const ushort8v*)(kbase + (size_t)(nkb + kk) * 128 + kd * 8);
        krg[1] = *(const ushort8v*)(kbase + (size_t)(nkb + kk + 32) * 128 + kd * 8);
        vrg[0] = *(const ushort8v*)(vbase + (size_t)vd * 2048 + nkb + vs * 8);
        vrg[1] = *(const ushort8v*)(vbase + (size_t)(vd + 64) * 2048 + nkb + vs * 8);
      }
      // wave fully causal-masked for this tile? (only possible on last iter)
      if (kb > q0 + wave * 16 + 15) continue;

      // S = scale * Q K^T  (16 q-rows x 64 keys per wave)
      float sv[4][4];
      for (int kt = 0; kt < 4; ++kt) {
        floatx4 a = {0.f, 0.f, 0.f, 0.f};
        for (int t = 0; t < 4; ++t) {
          bf16x8 kf = *(const bf16x8*)&k_lds[kt * 16 + l16][t * 32 + quad * 8];
          a = __builtin_amdgcn_mfma_f32_16x16x32_bf16(qf[t], kf, a, 0, 0, 0);
        }
        for (int r = 0; r < 4; ++r) sv[kt][r] = a[r] * scale;
      }
      if (kb + 63 > q0 + wave * 16) {  // tile touches the diagonal: causal mask
        for (int kt = 0; kt < 4; ++kt) {
          int kcol = kb + kt * 16 + l16;
          for (int r = 0; r < 4; ++r) {
            int qg = q0 + wave * 16 + quad * 4 + r;
            if (kcol > qg) sv[kt][r] -= 1.0e9f;
          }
        }
      }
      // online softmax with defer-max (THR=8)
      float mx[4];
      for (int r = 0; r < 4; ++r) {
        float m = fmaxf(fmaxf(sv[0][r], sv[1][r]), fmaxf(sv[2][r], sv[3][r]));
        for (int off = 1; off < 16; off <<= 1)
          m = fmaxf(m, __shfl_xor(m, off));
        mx[r] = m;
      }
      bool grow = false;
      for (int r = 0; r < 4; ++r) grow |= (mx[r] > m_i[r] + 8.f);
      if (__any(grow)) {
        for (int r = 0; r < 4; ++r) {
          float mnew = fmaxf(m_i[r], mx[r]);
          float alpha = __expf(m_i[r] - mnew);
          m_i[r] = mnew;
          l_i[r] *= alpha;
          for (int nb = 0; nb < 8; ++nb) o_acc[nb][r] *= alpha;
        }
      }
      for (int r = 0; r < 4; ++r) {
        float sum = 0.f;
        for (int kt = 0; kt < 4; ++kt) {
          float p = __expf(sv[kt][r] - m_i[r]);
          sv[kt][r] = p;
          sum += p;
        }
        for (int off = 1; off < 16; off <<= 1)
          sum += __shfl_xor(sum, off);
        l_i[r] += sum;
      }
      // P: C-layout -> LDS -> A-layout (m120 pattern); per-wave slice, so no
      // block barrier needed between write and read.
      for (int kt = 0; kt < 4; ++kt)
        for (int r = 0; r < 4; ++r)
          p_lds[wave][quad * 4 + r][kt * 16 + l16] = f2bf(sv[kt][r]);
      // O += P V
      for (int tk = 0; tk < 2; ++tk) {
        bf16x8 pa = *(const bf16x8*)&p_lds[wave][l16][tk * 32 + quad * 8];
        for (int nb = 0; nb < 8; ++nb) {
          bf16x8 vb = *(const bf16x8*)&v_lds[nb * 16 + l16][tk * 32 + quad * 8];
          o_acc[nb] = __builtin_amdgcn_mfma_f32_16x16x32_bf16(pa, vb, o_acc[nb], 0, 0, 0);
        }
      }
    }

    for (int nb = 0; nb < 8; ++nb)
      for (int r = 0; r < 4; ++r) {
        int row = b * 2048 + q0 + wave * 16 + quad * 4 + r;
        int col = h * 128 + nb * 16 + l16;
        O[(size_t)row * 4096 + col] = f2bf(o_acc[nb][r] / l_i[r]);
      }
  }
}

// ---------------------------------------------------------------------------
// Launcher.  Workspace layout (144 MB, with aliasing):
//   [0,   32M)  xb  (x in bf16)           -> later reused as Q (b,h,s,d)
//   [32M, 80M)  wT  (qkv weights, N x K)  -> later reused as w_oT
//   [80M, 128M) qkv (4096 x 6144 bf16)    -> later reused as O (attn out)
//   [128M,136M) Kd  (b,kvh,s,d)
//   [136M,144M) Vt  (b,kvh,d,s)
// ---------------------------------------------------------------------------
extern "C" void kernel_launch(void* const* d_in, const int* in_sizes, int n_in,
                              void* d_out, int out_size, void* d_ws, size_t ws_size,
                              hipStream_t stream) {
  const float* x   = (const float*)d_in[0];
  const float* w_q = (const float*)d_in[1];
  const float* w_k = (const float*)d_in[2];
  const float* w_v = (const float*)d_in[3];
  const float* w_o = (const float*)d_in[4];
  const float* fc  = (const float*)d_in[5];
  const float* fs  = (const float*)d_in[6];
  (void)in_sizes; (void)n_in; (void)out_size; (void)ws_size;

  char* ws = (char*)d_ws;
  unsigned short* xb  = (unsigned short*)(ws);
  unsigned short* wT  = (unsigned short*)(ws + 33554432ull);
  unsigned short* qkv = (unsigned short*)(ws + 83886080ull);
  unsigned short* Kd  = (unsigned short*)(ws + 134217728ull);
  unsigned short* Vt  = (unsigned short*)(ws + 142606336ull);
  unsigned short* Qd  = xb;   // alias: xb dead after gemm1
  unsigned short* woT = wT;   // alias: wT dead after gemm1
  unsigned short* Ob  = qkv;  // alias: qkv dead after rope/vtrans

  cvt_fp32_bf16<<<16384, 256, 0, stream>>>(x, xb, 4194304);
  transpose_cvt<<<dim3(128, 128), 256, 0, stream>>>(w_q, wT, 4096, 4096);
  transpose_cvt<<<dim3(128, 32), 256, 0, stream>>>(w_k, wT + (size_t)4096 * 4096, 4096, 1024);
  transpose_cvt<<<dim3(128, 32), 256, 0, stream>>>(w_v, wT + (size_t)5120 * 4096, 4096, 1024);
  gemm_bt<0><<<dim3(32, 48), 256, 0, stream>>>(xb, wT, qkv, 4096, 6144, 4096);
  transpose_cvt<<<dim3(128, 128), 256, 0, stream>>>(w_o, woT, 4096, 4096);
  rope_q<<<32768, 256, 0, stream>>>(qkv, fc, fs, Qd);
  rope_k<<<8192, 256, 0, stream>>>(qkv, fc, fs, Kd);
  vtrans<<<dim3(64, 4, 16), 256, 0, stream>>>(qkv, Vt);
  attn_kernel<<<dim3(8, 32, 2), 512, 0, stream>>>(Qd, Kd, Vt, Ob);
  gemm_bt<1><<<dim3(32, 32), 256, 0, stream>>>(Ob, woT, d_out, 4096, 4096, 4096);
}

// Round 5
// 794.321 us; speedup vs baseline: 1.2268x; 1.0287x over previous
//
#include <hip/hip_runtime.h>
#include <stdint.h>
#include <stddef.h>

// ---------------------------------------------------------------------------
// GQA forward: y = Attn(RoPE(x@Wq), RoPE(x@Wk), x@Wv) @ Wo
// B=2 S=2048 D=4096 H=32 KVH=8 Dh=128, causal, fp32 in/out, bf16 MFMA compute.
// ---------------------------------------------------------------------------

typedef __bf16 bf16x8 __attribute__((ext_vector_type(8)));
typedef float floatx4 __attribute__((ext_vector_type(4)));
typedef unsigned short ushort8v __attribute__((ext_vector_type(8)));
typedef unsigned short ushort4v __attribute__((ext_vector_type(4)));
typedef unsigned short ushort2v __attribute__((ext_vector_type(2)));

#define DEV static __device__ __forceinline__

DEV unsigned short f2bf(float f) {
  union { float f; unsigned u; } v; v.f = f;
  unsigned r = v.u + 0x7fffu + ((v.u >> 16) & 1u);
  return (unsigned short)(r >> 16);
}
DEV float bf2f(unsigned short b) {
  union { unsigned u; float f; } v; v.u = ((unsigned)b) << 16;
  return v.f;
}

// async global->LDS, 16B per lane; lds dest is wave-uniform base + lane*16
DEV void gload_lds16(const void* g, void* lds) {
  __builtin_amdgcn_global_load_lds(
      (__attribute__((address_space(1))) void*)(g),
      (__attribute__((address_space(3))) void*)(lds), 16, 0, 0);
}

// ---------------------------------------------------------------------------
// fp32 -> bf16 elementwise (x)
// ---------------------------------------------------------------------------
__global__ __launch_bounds__(256) void cvt_fp32_bf16(
    const float* __restrict__ in, unsigned short* __restrict__ out, int n4) {
  int i = blockIdx.x * 256 + threadIdx.x;
  if (i >= n4) return;
  float4 v = ((const float4*)in)[i];
  ushort4v w;
  w.x = f2bf(v.x); w.y = f2bf(v.y); w.z = f2bf(v.z); w.w = f2bf(v.w);
  *(ushort4v*)(out + (size_t)i * 4) = w;
}

// ---------------------------------------------------------------------------
// fp32 (K x N) -> bf16 (N x K) tiled transpose+convert
// ---------------------------------------------------------------------------
__global__ __launch_bounds__(256) void transpose_cvt(
    const float* __restrict__ in, unsigned short* __restrict__ out, int K, int N) {
  __shared__ float tile[32][33];
  int k0 = blockIdx.x * 32, n0 = blockIdx.y * 32;
  int tx = threadIdx.x & 31, ty = threadIdx.x >> 5;
  for (int i = 0; i < 32; i += 8)
    tile[ty + i][tx] = in[(size_t)(k0 + ty + i) * N + n0 + tx];
  __syncthreads();
  for (int i = 0; i < 32; i += 8)
    out[(size_t)(n0 + ty + i) * K + k0 + tx] = f2bf(tile[tx][ty + i]);
}

// ---------------------------------------------------------------------------
// GEMM, 256x256 tile, BK=64, 8 waves (2Mx4N), 8-phase counted-vmcnt schedule
// (T2 swizzle + T3/T4 pipeline + T5 setprio + T1 XCD swizzle).
// B supplied transposed (Bt[N,K]) -> A and B panels have identical layout.
//
// LDS: a_lds/b_lds = [2 dbuf][256 rows][8 chunks of 8 bf16]. Physical chunk
// position p of row r holds logical k-chunk p^(r&7)  (involution, applied on
// BOTH the staging source and the read side; LDS dest of global_load_lds
// stays linear per HW constraint). Fragment read (16 rows x same chunk)
// spreads over all 8 positions -> 2-way bank aliasing = free.
//
// Staging: half-tile = 128 rows x 64k = 16 issues x 1024B; wave w issues 2
// (rows h*128 + (w*2+j)*8 ..+7). Lane c: row += c>>3, phys chunk c&7,
// logical chunk (c&7)^(c>>3); 8 lanes/row cover a contiguous 128B segment.
//
// 8 phases / 2 K-tiles (even tile->buf0, odd->buf1). Phase:
//   [ds_read subtile][stage 1 half-tile][s_barrier][lgkmcnt(0)]
//   [setprio(1) 16 MFMA setprio(0)][s_barrier]
// Quadrants per K-tile: (0,0)(0,1)(1,1)(1,0); bLo stays in regs ph1-4 so
// no LDS region is re-read after its overwrite window opens.
// Freed (all waves, via closing barriers): B-halves after ph2/ph6, A-halves
// after ph3/ph7. Stages: ph1:(t+1).A0 ph2:(t+1).A1 ph3:(t+2).B0 ph4:(t+2).B1
// ph5:(t+2).A0 ph6:(t+2).A1 ph7:(t+3).B0 ph8:(t+3).B1 -- each targets a
// region freed >=1 phase earlier.
// vmcnt(4) at ph4/ph8 only (2 loads/half-tile x 2 half-tiles allowed in
// flight): at ph4 forces all of tile t+1 landed (read ph5-8); at ph8 all of
// t+2 (read next iter). Last iteration skips stages -> vmcnt(0) there.
// ---------------------------------------------------------------------------
#define LD8(LDS, D, ROW, Q)                                                  \
  (*(const bf16x8*)((const char*)(LDS) + (D) * 32768 + (ROW) * 128 +         \
                    (((Q) ^ ((ROW) & 7)) << 4)))

#define STAGE(PANEL, LDS, KT, H)                                             \
  {                                                                          \
    _Pragma("unroll") for (int j_ = 0; j_ < 2; ++j_) {                       \
      int t_ = wave * 2 + j_;                                                \
      int row_ = (H) * 128 + t_ * 8 + srow;                                  \
      gload_lds16(PANEL + (size_t)row_ * K + (size_t)(KT) * 64 + qsrc * 8,   \
                  (char*)(LDS) + ((KT) & 1) * 32768 + (H) * 16384 +          \
                      t_ * 1024);                                            \
    }                                                                        \
  }

#define READ_A(D, MH)                                                        \
  _Pragma("unroll") for (int mf_ = 0; mf_ < 4; ++mf_)                        \
      _Pragma("unroll") for (int kk_ = 0; kk_ < 2; ++kk_)                    \
          aR[mf_][kk_] =                                                     \
      LD8(a_lds, D, wm + ((MH) * 4 + mf_) * 16 + l16, kk_ * 4 + quad);

#define READ_B(D, NH, BREG)                                                  \
  _Pragma("unroll") for (int nf_ = 0; nf_ < 2; ++nf_)                        \
      _Pragma("unroll") for (int kk_ = 0; kk_ < 2; ++kk_)                    \
          BREG[nf_][kk_] =                                                   \
      LD8(b_lds, D, wn + ((NH) * 2 + nf_) * 16 + l16, kk_ * 4 + quad);

#define MFMA_Q(MH, NH, BREG)                                                 \
  _Pragma("unroll") for (int mf_ = 0; mf_ < 4; ++mf_)                        \
      _Pragma("unroll") for (int nf_ = 0; nf_ < 2; ++nf_)                    \
          _Pragma("unroll") for (int kk_ = 0; kk_ < 2; ++kk_)                \
              acc[(MH) * 4 + mf_][(NH) * 2 + nf_] =                          \
      __builtin_amdgcn_mfma_f32_16x16x32_bf16(                               \
          aR[mf_][kk_], BREG[nf_][kk_],                                      \
          acc[(MH) * 4 + mf_][(NH) * 2 + nf_], 0, 0, 0);

#define PH_SYNC_BEGIN                                                        \
  __builtin_amdgcn_s_barrier();                                              \
  asm volatile("s_waitcnt lgkmcnt(0)" ::: "memory");                         \
  __builtin_amdgcn_s_setprio(1);

#define PH_SYNC_END                                                          \
  __builtin_amdgcn_s_setprio(0);                                             \
  __builtin_amdgcn_s_barrier();

template <int STORE_F32>
__global__ __launch_bounds__(512, 2) void gemm_bt8(
    const unsigned short* __restrict__ A, const unsigned short* __restrict__ Bt,
    void* __restrict__ Cp, int M, int N, int K) {
  __shared__ __align__(16) unsigned short a_lds[32768];  // 64 KiB
  __shared__ __align__(16) unsigned short b_lds[32768];  // 64 KiB

  const int tid = threadIdx.x;
  const int wave = tid >> 6, lane = tid & 63;
  const int quad = lane >> 4, l16 = lane & 15;
  const int wm = (wave >> 2) * 128, wn = (wave & 3) * 64;

  // T1: bijective XCD swizzle on linearized id (grid counts are %8==0)
  const int gx = gridDim.x, gy = gridDim.y;
  int lid = blockIdx.y * gx + blockIdx.x;
  int cpx = (gx * gy) >> 3;
  int swz = (lid & 7) * cpx + (lid >> 3);
  const int m0 = (swz / gy) * 256, n0 = (swz % gy) * 256;

  const int qsrc = (lane & 7) ^ (lane >> 3);
  const int srow = lane >> 3;
  const unsigned short* Ab = A + (size_t)m0 * K;
  const unsigned short* Bb = Bt + (size_t)n0 * K;

  floatx4 acc[8][4] = {};
  bf16x8 aR[4][2], bLo[2][2], bHi[2][2];

  const int nt = K >> 6;      // K-tiles (even for all our shapes)
  const int iters = nt >> 1;

  // prologue: tile0 full -> buf0, tile1 B-halves -> buf1
  STAGE(Ab, a_lds, 0, 0); STAGE(Ab, a_lds, 0, 1);
  STAGE(Bb, b_lds, 0, 0); STAGE(Bb, b_lds, 0, 1);
  STAGE(Bb, b_lds, 1, 0); STAGE(Bb, b_lds, 1, 1);
  asm volatile("s_waitcnt vmcnt(0)" ::: "memory");
  __builtin_amdgcn_s_barrier();

  for (int i = 0; i < iters; ++i) {
    const int t0 = 2 * i;
    const bool has2 = (t0 + 2 < nt);
    // ======== K-tile t0 (buf 0) ========
    // ph1
    READ_A(0, 0); READ_B(0, 0, bLo);
    STAGE(Ab, a_lds, t0 + 1, 0);
    PH_SYNC_BEGIN; MFMA_Q(0, 0, bLo); PH_SYNC_END;
    // ph2
    READ_B(0, 1, bHi);
    STAGE(Ab, a_lds, t0 + 1, 1);
    PH_SYNC_BEGIN; MFMA_Q(0, 1, bHi); PH_SYNC_END;
    // ph3
    READ_A(0, 1);
    if (has2) STAGE(Bb, b_lds, t0 + 2, 0);
    PH_SYNC_BEGIN; MFMA_Q(1, 1, bHi); PH_SYNC_END;
    // ph4
    if (has2) {
      STAGE(Bb, b_lds, t0 + 2, 1);
      asm volatile("s_waitcnt vmcnt(4)" ::: "memory");
    } else {
      asm volatile("s_waitcnt vmcnt(0)" ::: "memory");
    }
    PH_SYNC_BEGIN; MFMA_Q(1, 0, bLo); PH_SYNC_END;
    // ======== K-tile t0+1 (buf 1) ========
    // ph5
    READ_A(1, 0); READ_B(1, 0, bLo);
    if (has2) STAGE(Ab, a_lds, t0 + 2, 0);
    PH_SYNC_BEGIN; MFMA_Q(0, 0, bLo); PH_SYNC_END;
    // ph6
    READ_B(1, 1, bHi);
    if (has2) STAGE(Ab, a_lds, t0 + 2, 1);
    PH_SYNC_BEGIN; MFMA_Q(0, 1, bHi); PH_SYNC_END;
    // ph7
    READ_A(1, 1);
    if (has2) STAGE(Bb, b_lds, t0 + 3, 0);
    PH_SYNC_BEGIN; MFMA_Q(1, 1, bHi); PH_SYNC_END;
    // ph8
    if (has2) {
      STAGE(Bb, b_lds, t0 + 3, 1);
      asm volatile("s_waitcnt vmcnt(4)" ::: "memory");
    } else {
      asm volatile("s_waitcnt vmcnt(0)" ::: "memory");
    }
    PH_SYNC_BEGIN; MFMA_Q(1, 0, bLo); PH_SYNC_END;
  }

#pragma unroll
  for (int mf = 0; mf < 8; ++mf)
#pragma unroll
    for (int nf = 0; nf < 4; ++nf)
#pragma unroll
      for (int r = 0; r < 4; ++r) {
        int row = m0 + wm + mf * 16 + quad * 4 + r;
        int col = n0 + wn + nf * 16 + l16;
        float v = acc[mf][nf][r];
        if (STORE_F32)
          ((float*)Cp)[(size_t)row * N + col] = v;
        else
          ((unsigned short*)Cp)[(size_t)row * N + col] = f2bf(v);
      }
}

// ---------------------------------------------------------------------------
// RoPE Q: qkv bf16 (4096 x 6144) cols [0,4096) -> Q (b,h,s,128) bf16
// ---------------------------------------------------------------------------
__global__ __launch_bounds__(256) void rope_q(
    const unsigned short* __restrict__ qkv, const float* __restrict__ fc,
    const float* __restrict__ fs, unsigned short* __restrict__ Qd) {
  int gid = blockIdx.x * 256 + threadIdx.x;  // B*S*H*64 = 8388608
  int i = gid & 63;
  int h = (gid >> 6) & 31;
  int s = (gid >> 11) & 2047;
  int b = gid >> 22;
  int row = b * 2048 + s;
  ushort2v p = *(const ushort2v*)(qkv + (size_t)row * 6144 + h * 128 + 2 * i);
  float a = bf2f(p.x), bb = bf2f(p.y);
  float c = fc[s * 64 + i], sn = fs[s * 64 + i];
  ushort2v w;
  w.x = f2bf(a * c - bb * sn);
  w.y = f2bf(a * sn + bb * c);
  *(ushort2v*)(Qd + ((((size_t)b * 32 + h) * 2048 + s) * 128 + 2 * i)) = w;
}

// ---------------------------------------------------------------------------
// RoPE K: qkv cols [4096,5120) -> K (b,kvh,s,128) bf16
// ---------------------------------------------------------------------------
__global__ __launch_bounds__(256) void rope_k(
    const unsigned short* __restrict__ qkv, const float* __restrict__ fc,
    const float* __restrict__ fs, unsigned short* __restrict__ Kd) {
  int gid = blockIdx.x * 256 + threadIdx.x;  // B*S*KVH*64 = 2097152
  int i = gid & 63;
  int kvh = (gid >> 6) & 7;
  int s = (gid >> 9) & 2047;
  int b = gid >> 20;
  int row = b * 2048 + s;
  ushort2v p = *(const ushort2v*)(qkv + (size_t)row * 6144 + 4096 + kvh * 128 + 2 * i);
  float a = bf2f(p.x), bb = bf2f(p.y);
  float c = fc[s * 64 + i], sn = fs[s * 64 + i];
  ushort2v w;
  w.x = f2bf(a * c - bb * sn);
  w.y = f2bf(a * sn + bb * c);
  *(ushort2v*)(Kd + ((((size_t)b * 8 + kvh) * 2048 + s) * 128 + 2 * i)) = w;
}

// ---------------------------------------------------------------------------
// V transpose: qkv cols [5120,6144) (s-major) -> Vt (b,kvh,128,2048) d-major
// ---------------------------------------------------------------------------
__global__ __launch_bounds__(256) void vtrans(
    const unsigned short* __restrict__ qkv, unsigned short* __restrict__ Vt) {
  __shared__ unsigned short tile[32][33];
  int bk = blockIdx.z;                 // b*8+kvh
  int b = bk >> 3, kvh = bk & 7;
  int s0 = blockIdx.x * 32, d0 = blockIdx.y * 32;
  int tx = threadIdx.x & 31, ty = threadIdx.x >> 5;
  for (int i = 0; i < 32; i += 8)
    tile[ty + i][tx] =
        qkv[(size_t)(b * 2048 + s0 + ty + i) * 6144 + 5120 + kvh * 128 + d0 + tx];
  __syncthreads();
  for (int i = 0; i < 32; i += 8)
    Vt[((size_t)bk * 128 + d0 + ty + i) * 2048 + s0 + tx] = tile[tx][ty + i];
}

// ---------------------------------------------------------------------------
// Flash attention, causal, GQA. One block = (b, h, TWO paired q-tiles of 128
// rows each); 8 waves each own 16 q-rows. 64-key iterations.
//
// Causal load balancing: q-tile i costs 2i+2 key-iterations (2..32). A block
// processes tile pr then tile 15-pr sequentially -> every block does exactly
// 34 iterations. Grid = 8x32x2 = 512 blocks = 2 blocks/CU resident in ONE
// generation -> no tail imbalance. Both passes share (b,kvh) K/V -> L2 reuse.
//
// Carried techniques: async-STAGE split (T14) via reg-staged K/V prefetch;
// 2 barriers/iter (p_lds is per-wave, no barrier before PV); defer-max
// (T13, THR=8); wave-level skip of fully-masked diagonal tiles.
// ---------------------------------------------------------------------------
__global__ __launch_bounds__(512, 4) void attn_kernel(
    const unsigned short* __restrict__ Q,   // (b,h,s,128)
    const unsigned short* __restrict__ Kd,  // (b,kvh,s,128)
    const unsigned short* __restrict__ Vt,  // (b,kvh,128,s)
    unsigned short* __restrict__ O) {       // (b*s, 4096)
  __shared__ __align__(16) unsigned short k_lds[64][136];   // [key][d] +pad
  __shared__ __align__(16) unsigned short v_lds[128][72];   // [d][key] +pad
  __shared__ __align__(16) unsigned short p_lds[8][16][72]; // per-wave P

  const int tid = threadIdx.x;
  const int wave = tid >> 6, lane = tid & 63;
  const int quad = lane >> 4, l16 = lane & 15;
  const int pr = blockIdx.x;           // 0..7 -> q-tiles {pr, 15-pr}
  const int h = blockIdx.y;
  const int b = blockIdx.z;
  const int kvh = h >> 2;
  const float scale = 0.08838834764831845f;  // 1/sqrt(128)

  const unsigned short* kbase = Kd + ((size_t)b * 8 + kvh) * 2048 * 128;
  const unsigned short* vbase = Vt + ((size_t)b * 8 + kvh) * 128 * 2048;

  const int kk = tid >> 4, kd = tid & 15;
  const int vd = tid >> 3, vs = tid & 7;

  for (int pass = 0; pass < 2; ++pass) {
    const int qt = pass == 0 ? pr : 15 - pr;
    const int q0 = qt * 128;

    const unsigned short* qrow =
        Q + (((size_t)b * 32 + h) * 2048 + q0 + wave * 16 + l16) * 128;
    bf16x8 qf[4];
    for (int t = 0; t < 4; ++t)
      qf[t] = *(const bf16x8*)(qrow + t * 32 + quad * 8);

    float m_i[4], l_i[4];
    for (int r = 0; r < 4; ++r) { m_i[r] = -3.0e38f; l_i[r] = 0.f; }
    floatx4 o_acc[8] = {};

    ushort8v krg[2], vrg[2];
    // prologue: load tile kb=0 into regs
    krg[0] = *(const ushort8v*)(kbase + (size_t)kk * 128 + kd * 8);
    krg[1] = *(const ushort8v*)(kbase + (size_t)(kk + 32) * 128 + kd * 8);
    vrg[0] = *(const ushort8v*)(vbase + (size_t)vd * 2048 + vs * 8);
    vrg[1] = *(const ushort8v*)(vbase + (size_t)(vd + 64) * 2048 + vs * 8);

    const int kb_last = q0 + 64;  // last 64-key tile needed by rows q0..q0+127
    for (int kb = 0; kb <= kb_last; kb += 64) {
      __syncthreads();  // previous tile's readers done
      *(ushort8v*)&k_lds[kk][kd * 8] = krg[0];
      *(ushort8v*)&k_lds[kk + 32][kd * 8] = krg[1];
      *(ushort8v*)&v_lds[vd][vs * 8] = vrg[0];
      *(ushort8v*)&v_lds[vd + 64][vs * 8] = vrg[1];
      __syncthreads();  // tile visible
      if (kb < kb_last) {  // issue next tile's loads; latency hides under compute
        int nkb = kb + 64;
        krg[0] = *(const ushort8v*)(kbase + (size_t)(nkb + kk) * 128 + kd * 8);
        krg[1] = *(const ushort8v*)(kbase + (size_t)(nkb + kk + 32) * 128 + kd * 8);
        vrg[0] = *(const ushort8v*)(vbase + (size_t)vd * 2048 + nkb + vs * 8);
        vrg[1] = *(const ushort8v*)(vbase + (size_t)(vd + 64) * 2048 + nkb + vs * 8);
      }
      // wave fully causal-masked for this tile? (only possible on last iter)
      if (kb > q0 + wave * 16 + 15) continue;

      // S = scale * Q K^T  (16 q-rows x 64 keys per wave)
      float sv[4][4];
      for (int kt = 0; kt < 4; ++kt) {
        floatx4 a = {0.f, 0.f, 0.f, 0.f};
        for (int t = 0; t < 4; ++t) {
          bf16x8 kf = *(const bf16x8*)&k_lds[kt * 16 + l16][t * 32 + quad * 8];
          a = __builtin_amdgcn_mfma_f32_16x16x32_bf16(qf[t], kf, a, 0, 0, 0);
        }
        for (int r = 0; r < 4; ++r) sv[kt][r] = a[r] * scale;
      }
      if (kb + 63 > q0 + wave * 16) {  // tile touches the diagonal: causal mask
        for (int kt = 0; kt < 4; ++kt) {
          int kcol = kb + kt * 16 + l16;
          for (int r = 0; r < 4; ++r) {
            int qg = q0 + wave * 16 + quad * 4 + r;
            if (kcol > qg) sv[kt][r] -= 1.0e9f;
          }
        }
      }
      // online softmax with defer-max (THR=8)
      float mx[4];
      for (int r = 0; r < 4; ++r) {
        float m = fmaxf(fmaxf(sv[0][r], sv[1][r]), fmaxf(sv[2][r], sv[3][r]));
        for (int off = 1; off < 16; off <<= 1)
          m = fmaxf(m, __shfl_xor(m, off));
        mx[r] = m;
      }
      bool grow = false;
      for (int r = 0; r < 4; ++r) grow |= (mx[r] > m_i[r] + 8.f);
      if (__any(grow)) {
        for (int r = 0; r < 4; ++r) {
          float mnew = fmaxf(m_i[r], mx[r]);
          float alpha = __expf(m_i[r] - mnew);
          m_i[r] = mnew;
          l_i[r] *= alpha;
          for (int nb = 0; nb < 8; ++nb) o_acc[nb][r] *= alpha;
        }
      }
      for (int r = 0; r < 4; ++r) {
        float sum = 0.f;
        for (int kt = 0; kt < 4; ++kt) {
          float p = __expf(sv[kt][r] - m_i[r]);
          sv[kt][r] = p;
          sum += p;
        }
        for (int off = 1; off < 16; off <<= 1)
          sum += __shfl_xor(sum, off);
        l_i[r] += sum;
      }
      // P: C-layout -> LDS -> A-layout; per-wave slice, no block barrier.
      for (int kt = 0; kt < 4; ++kt)
        for (int r = 0; r < 4; ++r)
          p_lds[wave][quad * 4 + r][kt * 16 + l16] = f2bf(sv[kt][r]);
      // O += P V
      for (int tk = 0; tk < 2; ++tk) {
        bf16x8 pa = *(const bf16x8*)&p_lds[wave][l16][tk * 32 + quad * 8];
        for (int nb = 0; nb < 8; ++nb) {
          bf16x8 vb = *(const bf16x8*)&v_lds[nb * 16 + l16][tk * 32 + quad * 8];
          o_acc[nb] = __builtin_amdgcn_mfma_f32_16x16x32_bf16(pa, vb, o_acc[nb], 0, 0, 0);
        }
      }
    }

    for (int nb = 0; nb < 8; ++nb)
      for (int r = 0; r < 4; ++r) {
        int row = b * 2048 + q0 + wave * 16 + quad * 4 + r;
        int col = h * 128 + nb * 16 + l16;
        O[(size_t)row * 4096 + col] = f2bf(o_acc[nb][r] / l_i[r]);
      }
  }
}

// ---------------------------------------------------------------------------
// Launcher.  Workspace layout (144 MB, with aliasing):
//   [0,   32M)  xb  (x in bf16)           -> later reused as Q (b,h,s,d)
//   [32M, 80M)  wT  (qkv weights, N x K)  -> later reused as w_oT
//   [80M, 128M) qkv (4096 x 6144 bf16)    -> later reused as O (attn out)
//   [128M,136M) Kd  (b,kvh,s,d)
//   [136M,144M) Vt  (b,kvh,d,s)
// ---------------------------------------------------------------------------
extern "C" void kernel_launch(void* const* d_in, const int* in_sizes, int n_in,
                              void* d_out, int out_size, void* d_ws, size_t ws_size,
                              hipStream_t stream) {
  const float* x   = (const float*)d_in[0];
  const float* w_q = (const float*)d_in[1];
  const float* w_k = (const float*)d_in[2];
  const float* w_v = (const float*)d_in[3];
  const float* w_o = (const float*)d_in[4];
  const float* fc  = (const float*)d_in[5];
  const float* fs  = (const float*)d_in[6];
  (void)in_sizes; (void)n_in; (void)out_size; (void)ws_size;

  char* ws = (char*)d_ws;
  unsigned short* xb  = (unsigned short*)(ws);
  unsigned short* wT  = (unsigned short*)(ws + 33554432ull);
  unsigned short* qkv = (unsigned short*)(ws + 83886080ull);
  unsigned short* Kd  = (unsigned short*)(ws + 134217728ull);
  unsigned short* Vt  = (unsigned short*)(ws + 142606336ull);
  unsigned short* Qd  = xb;   // alias: xb dead after gemm1
  unsigned short* woT = wT;   // alias: wT dead after gemm1
  unsigned short* Ob  = qkv;  // alias: qkv dead after rope/vtrans

  cvt_fp32_bf16<<<16384, 256, 0, stream>>>(x, xb, 4194304);
  transpose_cvt<<<dim3(128, 128), 256, 0, stream>>>(w_q, wT, 4096, 4096);
  transpose_cvt<<<dim3(128, 32), 256, 0, stream>>>(w_k, wT + (size_t)4096 * 4096, 4096, 1024);
  transpose_cvt<<<dim3(128, 32), 256, 0, stream>>>(w_v, wT + (size_t)5120 * 4096, 4096, 1024);
  gemm_bt8<0><<<dim3(16, 24), 512, 0, stream>>>(xb, wT, qkv, 4096, 6144, 4096);
  transpose_cvt<<<dim3(128, 128), 256, 0, stream>>>(w_o, woT, 4096, 4096);
  rope_q<<<32768, 256, 0, stream>>>(qkv, fc, fs, Qd);
  rope_k<<<8192, 256, 0, stream>>>(qkv, fc, fs, Kd);
  vtrans<<<dim3(64, 4, 16), 256, 0, stream>>>(qkv, Vt);
  attn_kernel<<<dim3(8, 32, 2), 512, 0, stream>>>(Qd, Kd, Vt, Ob);
  gemm_bt8<1><<<dim3(16, 16), 512, 0, stream>>>(Ob, woT, d_out, 4096, 4096, 4096);
}